// Round 3
// baseline (943.845 us; speedup 1.0000x reference)
//
#include <hip/hip_runtime.h>

// ============================================================================
// GLM4-MoE attention layer on MI355X (gfx950), fp16 MFMA pipeline.
// Round 3: swapped QK^T (S^T = K·Q^T) so q is lane-local in the C layout:
//   - in-lane row max (15 fmax + 2 shfl) instead of 32-shfl chains
//   - mask only on the single diagonal tile per wave
//   - P packed via v_cvt_pkrtz -> 8 ds_write_b64 (was 32 ds_write_b16)
//   - T13 defer-rescale (thr=8, log2 space), exp2-space with Q pre-scaled
//     by SM_SCALE*log2e in the GEMM1 epilogue
// K/V dbuf + vmcnt(8) + XOR swizzle + heavy-first unchanged (round-2 proven).
// GEMMs structurally unchanged (8-phase upgrade deferred to next round).
// ============================================================================

typedef _Float16 f16;
typedef _Float16 f16x8 __attribute__((ext_vector_type(8)));
typedef float f32x4 __attribute__((ext_vector_type(4)));

static constexpr int Bn = 2, Sn = 2048, Hn = 4096, NH = 32, NKV = 8, HD = 128;
static constexpr float SM_SCALE = 0.08838834764831845f; // 1/sqrt(128)
static constexpr float QSC = 0.08838834764831845f * 1.44269504088896340736f; // *log2e

#define AS1 __attribute__((address_space(1)))
#define AS3 __attribute__((address_space(3)))

__device__ __forceinline__ void async_ld16(const void* g, void* l) {
    __builtin_amdgcn_global_load_lds((const AS1 void*)g, (AS3 void*)l, 16, 0, 0);
}

// pack 2 f32 -> 2 f16 in one u32 (round-toward-zero)
__device__ __forceinline__ unsigned pk2(float a, float b) {
    unsigned r;
    asm("v_cvt_pkrtz_f16_f32 %0, %1, %2" : "=v"(r) : "v"(a), "v"(b));
    return r;
}

// ---------------------------------------------------------------------------
__global__ void k_cvt(const float* __restrict__ src, f16* __restrict__ dst, long n) {
    long i = ((long)blockIdx.x * blockDim.x + threadIdx.x) * 8;
    if (i >= n) return;
    float4 a = *(const float4*)(src + i);
    float4 b = *(const float4*)(src + i + 4);
    f16x8 o = {(f16)a.x, (f16)a.y, (f16)a.z, (f16)a.w,
               (f16)b.x, (f16)b.y, (f16)b.z, (f16)b.w};
    *(f16x8*)(dst + i) = o;
}

// ---------------------------------------------------------------------------
__global__ void k_tcvt(const float* __restrict__ src, f16* __restrict__ dst,
                       int K, int N, long rs) {
    __shared__ float tile[32][33];
    int k0 = blockIdx.y * 32, n0 = blockIdx.x * 32;
    int tx = threadIdx.x, ty = threadIdx.y;
#pragma unroll
    for (int r = ty; r < 32; r += 8)
        tile[r][tx] = src[(long)(k0 + r) * N + (n0 + tx)];
    __syncthreads();
#pragma unroll
    for (int r = ty; r < 32; r += 8)
        dst[(long)(n0 + r) * rs + (k0 + tx)] = (f16)tile[tx][r];
}

// ---------------------------------------------------------------------------
__global__ void k_rope(f16* __restrict__ x, const float* __restrict__ cosb,
                       const float* __restrict__ sinb, int nheads) {
    long idx = (long)blockIdx.x * blockDim.x + threadIdx.x;
    int i = (int)(idx & 31);
    long t = idx >> 5;
    int s = (int)(t & (Sn - 1));
    int bh = (int)(t >> 11);
    int b = bh / nheads;
    long base = t * HD + 2 * i;
    float c = cosb[((long)b * Sn + s) * 64 + i];
    float sv = sinb[((long)b * Sn + s) * 64 + i];
    float x0 = (float)x[base], x1 = (float)x[base + 1];
    x[base]     = (f16)(x0 * c - x1 * sv);
    x[base + 1] = (f16)(x1 * c + x0 * sv);
}

// ---------------------------------------------------------------------------
__global__ void k_tv(const f16* __restrict__ v, f16* __restrict__ vt) {
    __shared__ f16 tile[32][33];
    int bk = blockIdx.z;
    int s0 = blockIdx.x * 32, d0 = blockIdx.y * 32;
    const f16* src = v + (long)bk * Sn * HD;
    f16* dst = vt + (long)bk * Sn * HD;
    int tx = threadIdx.x, ty = threadIdx.y;
#pragma unroll
    for (int r = ty; r < 32; r += 8)
        tile[r][tx] = src[(long)(s0 + r) * HD + (d0 + tx)];
    __syncthreads();
#pragma unroll
    for (int r = ty; r < 32; r += 8)
        dst[(long)(d0 + r) * Sn + (s0 + tx)] = tile[tx][r];
}

// ---------------------------------------------------------------------------
// GEMM core (unchanged, known-good)
__device__ __forceinline__ void gemm_core(const f16* __restrict__ A,
                                          const f16* __restrict__ Bt,
                                          f16* Asm, f16* Bsm,
                                          int m0, int n0, f32x4 acc[4][4]) {
    const int t = threadIdx.x, lane = t & 63, wave = t >> 6;
    const int wr = wave >> 1, wc = wave & 1;
    const int fr = lane & 15, fg = lane >> 4;
    const int srow = t >> 2;
    const int scol = (t & 3) * 8;
    const f16* ga = A + (long)(m0 + srow) * 4096 + scol;
    const f16* gb = Bt + (long)(n0 + srow) * 4096 + scol;

    for (int k0 = 0; k0 < 4096; k0 += 32) {
        __syncthreads();
        async_ld16(ga + k0,               Asm + wave * 512);
        async_ld16(ga + 64 * 4096 + k0,   Asm + 2048 + wave * 512);
        async_ld16(gb + k0,               Bsm + wave * 512);
        async_ld16(gb + 64 * 4096 + k0,   Bsm + 2048 + wave * 512);
        asm volatile("s_waitcnt vmcnt(0)" ::: "memory");
        __syncthreads();

        f16x8 af[4], bf[4];
#pragma unroll
        for (int mm = 0; mm < 4; ++mm)
            af[mm] = *(const f16x8*)&Asm[(wr * 64 + mm * 16 + fr) * 32 + 8 * fg];
#pragma unroll
        for (int nn = 0; nn < 4; ++nn)
            bf[nn] = *(const f16x8*)&Bsm[(wc * 64 + nn * 16 + fr) * 32 + 8 * fg];
#pragma unroll
        for (int mm = 0; mm < 4; ++mm)
#pragma unroll
            for (int nn = 0; nn < 4; ++nn)
                acc[mm][nn] = __builtin_amdgcn_mfma_f32_16x16x32_f16(
                    af[mm], bf[nn], acc[mm][nn], 0, 0, 0);
    }
}

// GEMM1: hidden @ Wqkv^T -> scatter q/k/v. Q outputs pre-scaled by QSC.
__global__ __launch_bounds__(256) void k_gemm_qkv(
    const f16* __restrict__ A, const f16* __restrict__ Bt,
    f16* __restrict__ q, f16* __restrict__ kk_, f16* __restrict__ v) {
    __shared__ __align__(16) f16 Asm[128 * 32];
    __shared__ __align__(16) f16 Bsm[128 * 32];
    int n0 = blockIdx.x * 128, m0 = blockIdx.y * 128;
    f32x4 acc[4][4] = {};
    gemm_core(A, Bt, Asm, Bsm, m0, n0, acc);

    const int lane = threadIdx.x & 63, wave = threadIdx.x >> 6;
    const int wr = wave >> 1, wc = wave & 1;
    const int fr = lane & 15, fg = lane >> 4;
#pragma unroll
    for (int mm = 0; mm < 4; ++mm) {
        int r0 = m0 + wr * 64 + mm * 16 + 4 * fg;
#pragma unroll
        for (int nn = 0; nn < 4; ++nn) {
            int c = n0 + wc * 64 + nn * 16 + fr;
#pragma unroll
            for (int e = 0; e < 4; ++e) {
                int r = r0 + e;
                int b = r >> 11, s = r & (Sn - 1);
                int d = c & 127;
                if (c < 4096) {
                    int h = c >> 7;
                    q[(((long)b * NH + h) * Sn + s) * HD + d] = (f16)(acc[mm][nn][e] * QSC);
                } else if (c < 5120) {
                    int h = (c - 4096) >> 7;
                    kk_[(((long)b * NKV + h) * Sn + s) * HD + d] = (f16)acc[mm][nn][e];
                } else {
                    int h = (c - 5120) >> 7;
                    v[(((long)b * NKV + h) * Sn + s) * HD + d] = (f16)acc[mm][nn][e];
                }
            }
        }
    }
}

// GEMM2: attn_out @ wo^T -> f32
__global__ __launch_bounds__(256) void k_gemm_out(
    const f16* __restrict__ A, const f16* __restrict__ Bt,
    float* __restrict__ out) {
    __shared__ __align__(16) f16 Asm[128 * 32];
    __shared__ __align__(16) f16 Bsm[128 * 32];
    int n0 = blockIdx.x * 128, m0 = blockIdx.y * 128;
    f32x4 acc[4][4] = {};
    gemm_core(A, Bt, Asm, Bsm, m0, n0, acc);

    const int lane = threadIdx.x & 63, wave = threadIdx.x >> 6;
    const int wr = wave >> 1, wc = wave & 1;
    const int fr = lane & 15, fg = lane >> 4;
#pragma unroll
    for (int mm = 0; mm < 4; ++mm) {
        int r0 = m0 + wr * 64 + mm * 16 + 4 * fg;
#pragma unroll
        for (int nn = 0; nn < 4; ++nn) {
            int c = n0 + wc * 64 + nn * 16 + fr;
#pragma unroll
            for (int e = 0; e < 4; ++e)
                out[(long)(r0 + e) * 4096 + c] = acc[mm][nn][e];
        }
    }
}

// ---------------------------------------------------------------------------
// Flash attention v3: swapped QK^T, in-lane softmax, defer-rescale.
// QBLK=128 (4 waves x 32 q), KVBLK=64, K/V dbuf, vmcnt(8), XOR swizzle.

__device__ __forceinline__ f16x8 ld_sw256(const f16* base, int r, int c) {
    int byte = r * 256 + ((c * 2) ^ ((r & 7) << 4));
    return *(const f16x8*)((const char*)base + byte);
}
__device__ __forceinline__ f16x8 ld_sw128(const f16* base, int r, int c) {
    int byte = r * 128 + ((c * 2) ^ ((r & 7) << 4));
    return *(const f16x8*)((const char*)base + byte);
}

__device__ __forceinline__ void stage_k(const f16* __restrict__ Kb, f16* ksm,
                                        int k0, int wave, int lane) {
#pragma unroll
    for (int i = 0; i < 4; ++i) {
        int dbase = (i * 4 + wave) * 1024;
        int d = dbase + lane * 16;
        int row = d >> 8;
        int cb = (d & 255) ^ ((row & 7) << 4);
        async_ld16(Kb + (long)(k0 + row) * HD + (cb >> 1), (char*)ksm + dbase);
    }
}
__device__ __forceinline__ void stage_v(const f16* __restrict__ Vb, f16* vsm,
                                        int k0, int wave, int lane) {
#pragma unroll
    for (int i = 0; i < 4; ++i) {
        int dbase = (i * 4 + wave) * 1024;
        int d = dbase + lane * 16;
        int row = d >> 7;
        int cb = (d & 127) ^ ((row & 7) << 4);
        async_ld16(Vb + (long)row * Sn + k0 + (cb >> 1), (char*)vsm + dbase);
    }
}

__global__ __launch_bounds__(256) void k_attn(
    const f16* __restrict__ Q, const f16* __restrict__ K,
    const f16* __restrict__ Vt, f16* __restrict__ O) {
    __shared__ __align__(16) f16 Ksm[2][64 * 128];
    __shared__ __align__(16) f16 Vsm[2][128 * 64];
    __shared__ __align__(16) f16 Psm[4][32 * 64];

    const int qt = (gridDim.x - 1) - blockIdx.x;     // heavy-first
    const int q0 = qt * 128;
    const int h = blockIdx.y, b = blockIdx.z;
    const int kvh = h >> 2;
    const int t = threadIdx.x, lane = t & 63, wave = t >> 6;
    const int q0w = q0 + wave * 32;
    const int fr = lane & 15, fg = lane >> 4;

    const f16* Qb = Q + ((long)(b * NH + h) * Sn) * HD;
    const f16* Kb = K + ((long)(b * NKV + kvh) * Sn) * HD;
    const f16* Vb = Vt + ((long)(b * NKV + kvh) * HD) * Sn;

    // Q fragments (B-operand): lane needs Q[q = mq*16+fr][d = 32kk+8fg+e]
    f16x8 qf[2][4];
#pragma unroll
    for (int mq = 0; mq < 2; ++mq)
#pragma unroll
        for (int kk = 0; kk < 4; ++kk)
            qf[mq][kk] = *(const f16x8*)&Qb[(long)(q0w + mq * 16 + fr) * HD + kk * 32 + 8 * fg];

    f32x4 oacc[2][8] = {};
    float mrun[2] = {-1e30f, -1e30f};
    float lrun[2] = {0.f, 0.f};

    const int nt = q0 / 64 + 2;
    stage_k(Kb, Ksm[0], 0, wave, lane);
    stage_v(Vb, Vsm[0], 0, wave, lane);

    for (int kt = 0; kt < nt; ++kt) {
        const int k0 = kt * 64;
        const int cur = kt & 1;
        if (kt + 1 < nt) {
            stage_k(Kb, Ksm[cur ^ 1], (kt + 1) * 64, wave, lane);
            stage_v(Vb, Vsm[cur ^ 1], (kt + 1) * 64, wave, lane);
            asm volatile("s_waitcnt vmcnt(8)" ::: "memory");
        } else {
            asm volatile("s_waitcnt vmcnt(0)" ::: "memory");
        }
        __builtin_amdgcn_s_barrier();

        if (k0 <= q0w + 31) {
            // ---- S^T = K . Q^T : C layout -> kv = 16nn+4fg+e (rows), q = 16mq+fr (cols)
            f32x4 st[4][2] = {};
#pragma unroll
            for (int kk = 0; kk < 4; ++kk)
#pragma unroll
                for (int nn = 0; nn < 4; ++nn) {
                    f16x8 kf = ld_sw256(Ksm[cur], nn * 16 + fr, kk * 32 + 8 * fg);
#pragma unroll
                    for (int mq = 0; mq < 2; ++mq)
                        st[nn][mq] = __builtin_amdgcn_mfma_f32_16x16x32_f16(
                            kf, qf[mq][kk], st[nn][mq], 0, 0, 0);
                }
            // ---- mask only on diagonal tile (exactly one per wave)
            const bool full = (k0 + 63 <= q0w);
            if (!full) {
#pragma unroll
                for (int nn = 0; nn < 4; ++nn)
#pragma unroll
                    for (int mq = 0; mq < 2; ++mq)
#pragma unroll
                        for (int e = 0; e < 4; ++e) {
                            int kv = k0 + 16 * nn + 4 * fg + e;
                            int qq = q0w + 16 * mq + fr;
                            if (kv > qq) st[nn][mq][e] = -1e30f;
                        }
            }
            // ---- row max: in-lane (16 values) + cross-fg (xor 16, 32)
            float pmax[2];
#pragma unroll
            for (int mq = 0; mq < 2; ++mq) {
                float m0v = fmaxf(fmaxf(st[0][mq][0], st[0][mq][1]),
                                  fmaxf(st[0][mq][2], st[0][mq][3]));
#pragma unroll
                for (int nn = 1; nn < 4; ++nn) {
                    float mv = fmaxf(fmaxf(st[nn][mq][0], st[nn][mq][1]),
                                     fmaxf(st[nn][mq][2], st[nn][mq][3]));
                    m0v = fmaxf(m0v, mv);
                }
                m0v = fmaxf(m0v, __shfl_xor(m0v, 16, 64));
                m0v = fmaxf(m0v, __shfl_xor(m0v, 32, 64));
                pmax[mq] = m0v;
            }
            // ---- defer-rescale (T13): only when max grew past threshold
            bool need = (pmax[0] > mrun[0] + 8.f) || (pmax[1] > mrun[1] + 8.f);
            if (__any(need)) {
#pragma unroll
                for (int mq = 0; mq < 2; ++mq) {
                    float mn = fmaxf(mrun[mq], pmax[mq]);
                    float sc = exp2f(mrun[mq] - mn);
                    mrun[mq] = mn;
                    lrun[mq] *= sc;
                    float scr[4];
#pragma unroll
                    for (int e = 0; e < 4; ++e)
                        scr[e] = __shfl(sc, (lane & 48) | (4 * fg + e), 64);
#pragma unroll
                    for (int nd = 0; nd < 8; ++nd)
#pragma unroll
                        for (int e = 0; e < 4; ++e)
                            oacc[mq][nd][e] *= scr[e];
                }
            }
            // ---- P = exp2(st - mrun), pack 4 f16, one b64 write per (mq,nn)
#pragma unroll
            for (int mq = 0; mq < 2; ++mq) {
                int row = 16 * mq + fr;
                char* pbase = (char*)&Psm[wave][0] + row * 128;
                int rsw = (row & 7) << 4;
#pragma unroll
                for (int nn = 0; nn < 4; ++nn) {
                    float p0 = exp2f(st[nn][mq][0] - mrun[mq]);
                    float p1 = exp2f(st[nn][mq][1] - mrun[mq]);
                    float p2 = exp2f(st[nn][mq][2] - mrun[mq]);
                    float p3 = exp2f(st[nn][mq][3] - mrun[mq]);
                    lrun[mq] += (p0 + p1) + (p2 + p3);
                    uint2 w = {pk2(p0, p1), pk2(p2, p3)};
                    *(uint2*)(pbase + ((32 * nn + 8 * fg) ^ rsw)) = w;
                }
            }
            asm volatile("s_waitcnt lgkmcnt(0)" ::: "memory");
            __builtin_amdgcn_sched_barrier(0);
            // ---- PV: O += P(32x64) . V^T(64x128)  (layouts as round 2)
#pragma unroll
            for (int kk = 0; kk < 2; ++kk) {
                f16x8 pf[2];
#pragma unroll
                for (int mq = 0; mq < 2; ++mq)
                    pf[mq] = ld_sw128(Psm[wave], mq * 16 + fr, kk * 32 + 8 * fg);
#pragma unroll
                for (int nd = 0; nd < 8; ++nd) {
                    f16x8 vf = ld_sw128(Vsm[cur], nd * 16 + fr, kk * 32 + 8 * fg);
#pragma unroll
                    for (int mq = 0; mq < 2; ++mq)
                        oacc[mq][nd] = __builtin_amdgcn_mfma_f32_16x16x32_f16(
                            pf[mq], vf, oacc[mq][nd], 0, 0, 0);
                }
            }
        }
        __builtin_amdgcn_s_barrier();
    }

    // ---- epilogue: finish l (cross-fg sum), redistribute 1/l to C rows, store
#pragma unroll
    for (int mq = 0; mq < 2; ++mq) {
        lrun[mq] += __shfl_xor(lrun[mq], 16, 64);
        lrun[mq] += __shfl_xor(lrun[mq], 32, 64);
    }
#pragma unroll
    for (int mq = 0; mq < 2; ++mq) {
        float li = 1.f / lrun[mq];
        float ir[4];
#pragma unroll
        for (int e = 0; e < 4; ++e)
            ir[e] = __shfl(li, (lane & 48) | (4 * fg + e), 64);
#pragma unroll
        for (int nd = 0; nd < 8; ++nd)
#pragma unroll
            for (int e = 0; e < 4; ++e) {
                int srow = q0w + mq * 16 + 4 * fg + e;
                long tok = (long)b * Sn + srow;
                O[tok * (NH * HD) + h * HD + nd * 16 + fr] = (f16)(oacc[mq][nd][e] * ir[e]);
            }
    }
}

// sentinel if workspace too small
__global__ void k_ws_fail(float* out) { out[0] = 1.0e9f; }

// ---------------------------------------------------------------------------
extern "C" void kernel_launch(void* const* d_in, const int* in_sizes, int n_in,
                              void* d_out, int out_size, void* d_ws, size_t ws_size,
                              hipStream_t stream) {
    const float* hs   = (const float*)d_in[0];
    const float* wq   = (const float*)d_in[1];
    const float* wk   = (const float*)d_in[2];
    const float* wv   = (const float*)d_in[3];
    const float* wo   = (const float*)d_in[4];
    const float* cosb = (const float*)d_in[5];
    const float* sinb = (const float*)d_in[6];
    float* out = (float*)d_out;

    const size_t OFF_WQKV = 0;
    const size_t OFF_WO   = 50331648;
    const size_t OFF_HID  = 83886080;
    const size_t OFF_Q    = 117440512;
    const size_t OFF_K    = 150994944;
    const size_t OFF_V    = 159383552;
    const size_t OFF_VT   = 167772160;
    const size_t WS_NEED  = 176160768;
    if (ws_size < WS_NEED) { k_ws_fail<<<1, 1, 0, stream>>>(out); return; }

    char* ws = (char*)d_ws;
    f16* wqkv_t = (f16*)(ws + OFF_WQKV);
    f16* wo_t   = (f16*)(ws + OFF_WO);
    f16* hid    = (f16*)(ws + OFF_HID);
    f16* qb     = (f16*)(ws + OFF_Q);
    f16* kb     = (f16*)(ws + OFF_K);
    f16* vb     = (f16*)(ws + OFF_V);
    f16* vtb    = (f16*)(ws + OFF_VT);

    dim3 tb(32, 8);
    k_cvt<<<dim3(16777216 / (256 * 8)), 256, 0, stream>>>(hs, hid, 16777216L);
    k_tcvt<<<dim3(128, 128), tb, 0, stream>>>(wq, wqkv_t, 4096, 4096, 4096);
    k_tcvt<<<dim3(32, 128),  tb, 0, stream>>>(wk, wqkv_t + (long)4096 * 4096, 4096, 1024, 4096);
    k_tcvt<<<dim3(32, 128),  tb, 0, stream>>>(wv, wqkv_t + (long)5120 * 4096, 4096, 1024, 4096);
    k_tcvt<<<dim3(128, 128), tb, 0, stream>>>(wo, wo_t, 4096, 4096, 4096);
    k_gemm_qkv<<<dim3(48, 32), 256, 0, stream>>>(hid, wqkv_t, qb, kb, vb);
    k_rope<<<dim3(2 * 32 * 2048 * 32 / 256), 256, 0, stream>>>(qb, cosb, sinb, NH);
    k_rope<<<dim3(2 * 8 * 2048 * 32 / 256), 256, 0, stream>>>(kb, cosb, sinb, NKV);
    k_tv<<<dim3(64, 4, 16), tb, 0, stream>>>(vb, vtb);
    k_attn<<<dim3(16, 32, 2), 256, 0, stream>>>(qb, kb, vtb, hid);
    k_gemm_out<<<dim3(32, 32), 256, 0, stream>>>(hid, wo_t, out);
}

// Round 4
// 802.300 us; speedup vs baseline: 1.1764x; 1.1764x over previous
//
#include <hip/hip_runtime.h>

// ============================================================================
// GLM4-MoE attention layer on MI355X (gfx950), fp16 MFMA pipeline.
// Round 4: GEMMs rewritten to the 256x256 / BK=64 / 8-wave phase-pipelined
// structure (m201-class): LDS 128KB dbuf, XOR-swizzled tiles, per-phase
// {ds_read || stage -> s_barrier -> 16 MFMA (setprio) -> s_barrier},
// vmcnt(0) once per K-tile (issued 2-3 phases earlier => nearly free),
// XCD-bijective block swizzle. Attention v3 unchanged from round 3.
// ============================================================================

typedef _Float16 f16;
typedef _Float16 f16x8 __attribute__((ext_vector_type(8)));
typedef float f32x4 __attribute__((ext_vector_type(4)));

static constexpr int Bn = 2, Sn = 2048, Hn = 4096, NH = 32, NKV = 8, HD = 128;
static constexpr float QSC = 0.08838834764831845f * 1.44269504088896340736f; // 1/sqrt(128)*log2e

#define AS1 __attribute__((address_space(1)))
#define AS3 __attribute__((address_space(3)))

__device__ __forceinline__ void async_ld16(const void* g, void* l) {
    __builtin_amdgcn_global_load_lds((const AS1 void*)g, (AS3 void*)l, 16, 0, 0);
}

__device__ __forceinline__ unsigned pk2(float a, float b) {
    unsigned r;
    asm("v_cvt_pkrtz_f16_f32 %0, %1, %2" : "=v"(r) : "v"(a), "v"(b));
    return r;
}

// ---------------------------------------------------------------------------
__global__ void k_cvt(const float* __restrict__ src, f16* __restrict__ dst, long n) {
    long i = ((long)blockIdx.x * blockDim.x + threadIdx.x) * 8;
    if (i >= n) return;
    float4 a = *(const float4*)(src + i);
    float4 b = *(const float4*)(src + i + 4);
    f16x8 o = {(f16)a.x, (f16)a.y, (f16)a.z, (f16)a.w,
               (f16)b.x, (f16)b.y, (f16)b.z, (f16)b.w};
    *(f16x8*)(dst + i) = o;
}

// ---------------------------------------------------------------------------
__global__ void k_tcvt(const float* __restrict__ src, f16* __restrict__ dst,
                       int K, int N, long rs) {
    __shared__ float tile[32][33];
    int k0 = blockIdx.y * 32, n0 = blockIdx.x * 32;
    int tx = threadIdx.x, ty = threadIdx.y;
#pragma unroll
    for (int r = ty; r < 32; r += 8)
        tile[r][tx] = src[(long)(k0 + r) * N + (n0 + tx)];
    __syncthreads();
#pragma unroll
    for (int r = ty; r < 32; r += 8)
        dst[(long)(n0 + r) * rs + (k0 + tx)] = (f16)tile[tx][r];
}

// ---------------------------------------------------------------------------
__global__ void k_rope(f16* __restrict__ x, const float* __restrict__ cosb,
                       const float* __restrict__ sinb, int nheads) {
    long idx = (long)blockIdx.x * blockDim.x + threadIdx.x;
    int i = (int)(idx & 31);
    long t = idx >> 5;
    int s = (int)(t & (Sn - 1));
    int bh = (int)(t >> 11);
    int b = bh / nheads;
    long base = t * HD + 2 * i;
    float c = cosb[((long)b * Sn + s) * 64 + i];
    float sv = sinb[((long)b * Sn + s) * 64 + i];
    float x0 = (float)x[base], x1 = (float)x[base + 1];
    x[base]     = (f16)(x0 * c - x1 * sv);
    x[base + 1] = (f16)(x1 * c + x0 * sv);
}

// ---------------------------------------------------------------------------
__global__ void k_tv(const f16* __restrict__ v, f16* __restrict__ vt) {
    __shared__ f16 tile[32][33];
    int bk = blockIdx.z;
    int s0 = blockIdx.x * 32, d0 = blockIdx.y * 32;
    const f16* src = v + (long)bk * Sn * HD;
    f16* dst = vt + (long)bk * Sn * HD;
    int tx = threadIdx.x, ty = threadIdx.y;
#pragma unroll
    for (int r = ty; r < 32; r += 8)
        tile[r][tx] = src[(long)(s0 + r) * HD + (d0 + tx)];
    __syncthreads();
#pragma unroll
    for (int r = ty; r < 32; r += 8)
        dst[(long)(d0 + r) * Sn + (s0 + tx)] = tile[tx][r];
}

// ---------------------------------------------------------------------------
// 256x256 GEMM core, BK=64, 8 waves (2M x 4N), K=4096 fixed.
// A [M][4096] row-major f16; Bt [N][4096] row-major f16 (B pre-transposed).
// LDS layout (131072 B): buf c at c*65536; A halves at +0,+16384; B at +32768.
// Tile rows swizzled: logical (r, colbyte cb) at byte r*128 + (cb ^ ((r&7)<<4)).
// Per K-tile: 4 phases (mq x ks). Stages for tile t+1 issued in phases 1-2;
// vmcnt(0) at end of phase 4 (loads then 2-3 phases old). s_barrier pairs
// keep waves in lockstep; setprio(1) wraps each MFMA cluster (T5).
__device__ __forceinline__ void gemm256_core(
    const f16* __restrict__ A, const f16* __restrict__ Bt,
    char* L, int m0, int n0, f32x4 acc[8][4]) {
    const int t = threadIdx.x, lane = t & 63, wave = t >> 6;
    const int wm = wave >> 2, wn = wave & 3;
    const int fr = lane & 15, fg = lane >> 4;

    // staging geometry: row = half*128 + inst*64 + wave*8 + lane/8,
    // col elems = 8*((lane&7)^(lane>>3))  (inverse of the LDS read swizzle)
    const int srow = wave * 8 + (lane >> 3);
    const int scol = 8 * ((lane & 7) ^ (lane >> 3));
    const f16* ga = A  + (long)(m0 + srow) * 4096 + scol;
    const f16* gb = Bt + (long)(n0 + srow) * 4096 + scol;
    const int dst0 = wave * 1024;

    // prologue: stage tile 0 into buf 0 (A: 4 insts, B: 4 insts per wave)
#pragma unroll
    for (int half = 0; half < 2; ++half)
#pragma unroll
        for (int inst = 0; inst < 2; ++inst) {
            async_ld16(ga + (long)(half * 128 + inst * 64) * 4096,
                       L + half * 16384 + inst * 8192 + dst0);
            async_ld16(gb + (long)(half * 128 + inst * 64) * 4096,
                       L + 32768 + half * 16384 + inst * 8192 + dst0);
        }
    asm volatile("s_waitcnt vmcnt(0)" ::: "memory");
    __builtin_amdgcn_s_barrier();

    const int aoff = wm * 16384;
    const int boff = 32768 + (wn >> 1) * 16384;
    const int brow = (wn & 1) * 64;
    const int swz = (fr & 7) << 4;

    for (int tt = 0; tt < 64; ++tt) {
        const int c = tt & 1;
        const char* bufA = L + c * 65536 + aoff;
        const char* bufB = L + c * 65536 + boff;
        char* outbuf = L + (c ^ 1) * 65536;
        const f16* gat = ga + (tt + 1) * 64;
        const f16* gbt = gb + (tt + 1) * 64;
        const bool more = (tt < 63);

#pragma unroll
        for (int ks = 0; ks < 2; ++ks) {
            const int cb = (ks * 64 + 16 * fg) ^ swz;
            // B fragments for this kstep (used by both m-quads)
            f16x8 bf[4];
#pragma unroll
            for (int nf = 0; nf < 4; ++nf)
                bf[nf] = *(const f16x8*)(bufB + (brow + nf * 16 + fr) * 128 + cb);
#pragma unroll
            for (int mq = 0; mq < 2; ++mq) {
                f16x8 af[4];
#pragma unroll
                for (int i = 0; i < 4; ++i)
                    af[i] = *(const f16x8*)(bufA + (mq * 64 + i * 16 + fr) * 128 + cb);
                if (ks == 0 && more) {
                    if (mq == 0) {      // phase 1: stage next A halves
#pragma unroll
                        for (int half = 0; half < 2; ++half)
#pragma unroll
                            for (int inst = 0; inst < 2; ++inst)
                                async_ld16(gat + (long)(half * 128 + inst * 64) * 4096,
                                           outbuf + half * 16384 + inst * 8192 + dst0);
                    } else {            // phase 2: stage next B halves
#pragma unroll
                        for (int half = 0; half < 2; ++half)
#pragma unroll
                            for (int inst = 0; inst < 2; ++inst)
                                async_ld16(gbt + (long)(half * 128 + inst * 64) * 4096,
                                           outbuf + 32768 + half * 16384 + inst * 8192 + dst0);
                    }
                }
                __builtin_amdgcn_s_barrier();
                __builtin_amdgcn_s_setprio(1);
#pragma unroll
                for (int i = 0; i < 4; ++i)
#pragma unroll
                    for (int nf = 0; nf < 4; ++nf)
                        acc[mq * 4 + i][nf] = __builtin_amdgcn_mfma_f32_16x16x32_f16(
                            af[i], bf[nf], acc[mq * 4 + i][nf], 0, 0, 0);
                __builtin_amdgcn_s_setprio(0);
                if (ks == 1 && mq == 1)  // end of K-tile: drain next tile's stages
                    asm volatile("s_waitcnt vmcnt(0)" ::: "memory");
                __builtin_amdgcn_s_barrier();
            }
        }
    }
}

// GEMM1: hidden[4096][4096] @ Wqkv^T[6144][4096] -> scatter q/k/v (Q pre-scaled)
__global__ __launch_bounds__(512) void k_gemm_qkv(
    const f16* __restrict__ A, const f16* __restrict__ Bt,
    f16* __restrict__ q, f16* __restrict__ kk_, f16* __restrict__ vv) {
    __shared__ __align__(16) char L[131072];
    const int bid = blockIdx.x;                       // 384 blocks, %8==0
    const int swzb = (bid & 7) * 48 + (bid >> 3);     // XCD-bijective
    const int m0 = (swzb / 24) * 256, n0 = (swzb % 24) * 256;
    f32x4 acc[8][4] = {};
    gemm256_core(A, Bt, L, m0, n0, acc);

    const int lane = threadIdx.x & 63, wave = threadIdx.x >> 6;
    const int wm = wave >> 2, wn = wave & 3;
    const int fr = lane & 15, fg = lane >> 4;
#pragma unroll
    for (int mf = 0; mf < 8; ++mf) {
        int r0 = m0 + wm * 128 + mf * 16 + 4 * fg;
#pragma unroll
        for (int nf = 0; nf < 4; ++nf) {
            int cc = n0 + wn * 64 + nf * 16 + fr;
            int d = cc & 127;
#pragma unroll
            for (int e = 0; e < 4; ++e) {
                int r = r0 + e;
                int b = r >> 11, s = r & (Sn - 1);
                if (cc < 4096) {
                    int h = cc >> 7;
                    q[(((long)b * NH + h) * Sn + s) * HD + d] = (f16)(acc[mf][nf][e] * QSC);
                } else if (cc < 5120) {
                    int h = (cc - 4096) >> 7;
                    kk_[(((long)b * NKV + h) * Sn + s) * HD + d] = (f16)acc[mf][nf][e];
                } else {
                    int h = (cc - 5120) >> 7;
                    vv[(((long)b * NKV + h) * Sn + s) * HD + d] = (f16)acc[mf][nf][e];
                }
            }
        }
    }
}

// GEMM2: attn_out[4096][4096] @ wo^T[4096][4096] -> d_out f32
__global__ __launch_bounds__(512) void k_gemm_out(
    const f16* __restrict__ A, const f16* __restrict__ Bt,
    float* __restrict__ out) {
    __shared__ __align__(16) char L[131072];
    const int bid = blockIdx.x;                       // 256 blocks
    const int swzb = (bid & 7) * 32 + (bid >> 3);
    const int m0 = (swzb >> 4) * 256, n0 = (swzb & 15) * 256;
    f32x4 acc[8][4] = {};
    gemm256_core(A, Bt, L, m0, n0, acc);

    const int lane = threadIdx.x & 63, wave = threadIdx.x >> 6;
    const int wm = wave >> 2, wn = wave & 3;
    const int fr = lane & 15, fg = lane >> 4;
#pragma unroll
    for (int mf = 0; mf < 8; ++mf) {
        int r0 = m0 + wm * 128 + mf * 16 + 4 * fg;
#pragma unroll
        for (int nf = 0; nf < 4; ++nf) {
            int cc = n0 + wn * 64 + nf * 16 + fr;
#pragma unroll
            for (int e = 0; e < 4; ++e)
                out[(long)(r0 + e) * 4096 + cc] = acc[mf][nf][e];
        }
    }
}

// ---------------------------------------------------------------------------
// Flash attention v3 (round-3 proven): swapped QK^T, in-lane softmax,
// defer-rescale, K/V dbuf + vmcnt(8) + XOR swizzle, heavy-first.

__device__ __forceinline__ f16x8 ld_sw256(const f16* base, int r, int c) {
    int byte = r * 256 + ((c * 2) ^ ((r & 7) << 4));
    return *(const f16x8*)((const char*)base + byte);
}
__device__ __forceinline__ f16x8 ld_sw128(const f16* base, int r, int c) {
    int byte = r * 128 + ((c * 2) ^ ((r & 7) << 4));
    return *(const f16x8*)((const char*)base + byte);
}

__device__ __forceinline__ void stage_k(const f16* __restrict__ Kb, f16* ksm,
                                        int k0, int wave, int lane) {
#pragma unroll
    for (int i = 0; i < 4; ++i) {
        int dbase = (i * 4 + wave) * 1024;
        int d = dbase + lane * 16;
        int row = d >> 8;
        int cb = (d & 255) ^ ((row & 7) << 4);
        async_ld16(Kb + (long)(k0 + row) * HD + (cb >> 1), (char*)ksm + dbase);
    }
}
__device__ __forceinline__ void stage_v(const f16* __restrict__ Vb, f16* vsm,
                                        int k0, int wave, int lane) {
#pragma unroll
    for (int i = 0; i < 4; ++i) {
        int dbase = (i * 4 + wave) * 1024;
        int d = dbase + lane * 16;
        int row = d >> 7;
        int cb = (d & 127) ^ ((row & 7) << 4);
        async_ld16(Vb + (long)row * Sn + k0 + (cb >> 1), (char*)vsm + dbase);
    }
}

__global__ __launch_bounds__(256) void k_attn(
    const f16* __restrict__ Q, const f16* __restrict__ K,
    const f16* __restrict__ Vt, f16* __restrict__ O) {
    __shared__ __align__(16) f16 Ksm[2][64 * 128];
    __shared__ __align__(16) f16 Vsm[2][128 * 64];
    __shared__ __align__(16) f16 Psm[4][32 * 64];

    const int qt = (gridDim.x - 1) - blockIdx.x;     // heavy-first
    const int q0 = qt * 128;
    const int h = blockIdx.y, b = blockIdx.z;
    const int kvh = h >> 2;
    const int t = threadIdx.x, lane = t & 63, wave = t >> 6;
    const int q0w = q0 + wave * 32;
    const int fr = lane & 15, fg = lane >> 4;

    const f16* Qb = Q + ((long)(b * NH + h) * Sn) * HD;
    const f16* Kb = K + ((long)(b * NKV + kvh) * Sn) * HD;
    const f16* Vb = Vt + ((long)(b * NKV + kvh) * HD) * Sn;

    f16x8 qf[2][4];
#pragma unroll
    for (int mq = 0; mq < 2; ++mq)
#pragma unroll
        for (int kk = 0; kk < 4; ++kk)
            qf[mq][kk] = *(const f16x8*)&Qb[(long)(q0w + mq * 16 + fr) * HD + kk * 32 + 8 * fg];

    f32x4 oacc[2][8] = {};
    float mrun[2] = {-1e30f, -1e30f};
    float lrun[2] = {0.f, 0.f};

    const int nt = q0 / 64 + 2;
    stage_k(Kb, Ksm[0], 0, wave, lane);
    stage_v(Vb, Vsm[0], 0, wave, lane);

    for (int kt = 0; kt < nt; ++kt) {
        const int k0 = kt * 64;
        const int cur = kt & 1;
        if (kt + 1 < nt) {
            stage_k(Kb, Ksm[cur ^ 1], (kt + 1) * 64, wave, lane);
            stage_v(Vb, Vsm[cur ^ 1], (kt + 1) * 64, wave, lane);
            asm volatile("s_waitcnt vmcnt(8)" ::: "memory");
        } else {
            asm volatile("s_waitcnt vmcnt(0)" ::: "memory");
        }
        __builtin_amdgcn_s_barrier();

        if (k0 <= q0w + 31) {
            f32x4 st[4][2] = {};
#pragma unroll
            for (int kk = 0; kk < 4; ++kk)
#pragma unroll
                for (int nn = 0; nn < 4; ++nn) {
                    f16x8 kf = ld_sw256(Ksm[cur], nn * 16 + fr, kk * 32 + 8 * fg);
#pragma unroll
                    for (int mq = 0; mq < 2; ++mq)
                        st[nn][mq] = __builtin_amdgcn_mfma_f32_16x16x32_f16(
                            kf, qf[mq][kk], st[nn][mq], 0, 0, 0);
                }
            const bool full = (k0 + 63 <= q0w);
            if (!full) {
#pragma unroll
                for (int nn = 0; nn < 4; ++nn)
#pragma unroll
                    for (int mq = 0; mq < 2; ++mq)
#pragma unroll
                        for (int e = 0; e < 4; ++e) {
                            int kv = k0 + 16 * nn + 4 * fg + e;
                            int qq = q0w + 16 * mq + fr;
                            if (kv > qq) st[nn][mq][e] = -1e30f;
                        }
            }
            float pmax[2];
#pragma unroll
            for (int mq = 0; mq < 2; ++mq) {
                float m0v = fmaxf(fmaxf(st[0][mq][0], st[0][mq][1]),
                                  fmaxf(st[0][mq][2], st[0][mq][3]));
#pragma unroll
                for (int nn = 1; nn < 4; ++nn) {
                    float mv = fmaxf(fmaxf(st[nn][mq][0], st[nn][mq][1]),
                                     fmaxf(st[nn][mq][2], st[nn][mq][3]));
                    m0v = fmaxf(m0v, mv);
                }
                m0v = fmaxf(m0v, __shfl_xor(m0v, 16, 64));
                m0v = fmaxf(m0v, __shfl_xor(m0v, 32, 64));
                pmax[mq] = m0v;
            }
            bool need = (pmax[0] > mrun[0] + 8.f) || (pmax[1] > mrun[1] + 8.f);
            if (__any(need)) {
#pragma unroll
                for (int mq = 0; mq < 2; ++mq) {
                    float mn = fmaxf(mrun[mq], pmax[mq]);
                    float sc = exp2f(mrun[mq] - mn);
                    mrun[mq] = mn;
                    lrun[mq] *= sc;
                    float scr[4];
#pragma unroll
                    for (int e = 0; e < 4; ++e)
                        scr[e] = __shfl(sc, (lane & 48) | (4 * fg + e), 64);
#pragma unroll
                    for (int nd = 0; nd < 8; ++nd)
#pragma unroll
                        for (int e = 0; e < 4; ++e)
                            oacc[mq][nd][e] *= scr[e];
                }
            }
#pragma unroll
            for (int mq = 0; mq < 2; ++mq) {
                int row = 16 * mq + fr;
                char* pbase = (char*)&Psm[wave][0] + row * 128;
                int rsw = (row & 7) << 4;
#pragma unroll
                for (int nn = 0; nn < 4; ++nn) {
                    float p0 = exp2f(st[nn][mq][0] - mrun[mq]);
                    float p1 = exp2f(st[nn][mq][1] - mrun[mq]);
                    float p2 = exp2f(st[nn][mq][2] - mrun[mq]);
                    float p3 = exp2f(st[nn][mq][3] - mrun[mq]);
                    lrun[mq] += (p0 + p1) + (p2 + p3);
                    uint2 w = {pk2(p0, p1), pk2(p2, p3)};
                    *(uint2*)(pbase + ((32 * nn + 8 * fg) ^ rsw)) = w;
                }
            }
            asm volatile("s_waitcnt lgkmcnt(0)" ::: "memory");
            __builtin_amdgcn_sched_barrier(0);
#pragma unroll
            for (int kk = 0; kk < 2; ++kk) {
                f16x8 pf[2];
#pragma unroll
                for (int mq = 0; mq < 2; ++mq)
                    pf[mq] = ld_sw128(Psm[wave], mq * 16 + fr, kk * 32 + 8 * fg);
#pragma unroll
                for (int nd = 0; nd < 8; ++nd) {
                    f16x8 vf = ld_sw128(Vsm[cur], nd * 16 + fr, kk * 32 + 8 * fg);
#pragma unroll
                    for (int mq = 0; mq < 2; ++mq)
                        oacc[mq][nd] = __builtin_amdgcn_mfma_f32_16x16x32_f16(
                            pf[mq], vf, oacc[mq][nd], 0, 0, 0);
                }
            }
        }
        __builtin_amdgcn_s_barrier();
    }

#pragma unroll
    for (int mq = 0; mq < 2; ++mq) {
        lrun[mq] += __shfl_xor(lrun[mq], 16, 64);
        lrun[mq] += __shfl_xor(lrun[mq], 32, 64);
    }
#pragma unroll
    for (int mq = 0; mq < 2; ++mq) {
        float li = 1.f / lrun[mq];
        float ir[4];
#pragma unroll
        for (int e = 0; e < 4; ++e)
            ir[e] = __shfl(li, (lane & 48) | (4 * fg + e), 64);
#pragma unroll
        for (int nd = 0; nd < 8; ++nd)
#pragma unroll
            for (int e = 0; e < 4; ++e) {
                int srow = q0w + mq * 16 + 4 * fg + e;
                long tok = (long)b * Sn + srow;
                O[tok * (NH * HD) + h * HD + nd * 16 + fr] = (f16)(oacc[mq][nd][e] * ir[e]);
            }
    }
}

// sentinel if workspace too small
__global__ void k_ws_fail(float* out) { out[0] = 1.0e9f; }

// ---------------------------------------------------------------------------
extern "C" void kernel_launch(void* const* d_in, const int* in_sizes, int n_in,
                              void* d_out, int out_size, void* d_ws, size_t ws_size,
                              hipStream_t stream) {
    const float* hs   = (const float*)d_in[0];
    const float* wq   = (const float*)d_in[1];
    const float* wk   = (const float*)d_in[2];
    const float* wv   = (const float*)d_in[3];
    const float* wo   = (const float*)d_in[4];
    const float* cosb = (const float*)d_in[5];
    const float* sinb = (const float*)d_in[6];
    float* out = (float*)d_out;

    const size_t OFF_WQKV = 0;
    const size_t OFF_WO   = 50331648;
    const size_t OFF_HID  = 83886080;
    const size_t OFF_Q    = 117440512;
    const size_t OFF_K    = 150994944;
    const size_t OFF_V    = 159383552;
    const size_t OFF_VT   = 167772160;
    const size_t WS_NEED  = 176160768;
    if (ws_size < WS_NEED) { k_ws_fail<<<1, 1, 0, stream>>>(out); return; }

    char* ws = (char*)d_ws;
    f16* wqkv_t = (f16*)(ws + OFF_WQKV);
    f16* wo_t   = (f16*)(ws + OFF_WO);
    f16* hid    = (f16*)(ws + OFF_HID);
    f16* qb     = (f16*)(ws + OFF_Q);
    f16* kb     = (f16*)(ws + OFF_K);
    f16* vb     = (f16*)(ws + OFF_V);
    f16* vtb    = (f16*)(ws + OFF_VT);

    dim3 tb(32, 8);
    k_cvt<<<dim3(16777216 / (256 * 8)), 256, 0, stream>>>(hs, hid, 16777216L);
    k_tcvt<<<dim3(128, 128), tb, 0, stream>>>(wq, wqkv_t, 4096, 4096, 4096);
    k_tcvt<<<dim3(32, 128),  tb, 0, stream>>>(wk, wqkv_t + (long)4096 * 4096, 4096, 1024, 4096);
    k_tcvt<<<dim3(32, 128),  tb, 0, stream>>>(wv, wqkv_t + (long)5120 * 4096, 4096, 1024, 4096);
    k_tcvt<<<dim3(128, 128), tb, 0, stream>>>(wo, wo_t, 4096, 4096, 4096);
    k_gemm_qkv<<<dim3(384), 512, 0, stream>>>(hid, wqkv_t, qb, kb, vb);
    k_rope<<<dim3(2 * 32 * 2048 * 32 / 256), 256, 0, stream>>>(qb, cosb, sinb, NH);
    k_rope<<<dim3(2 * 8 * 2048 * 32 / 256), 256, 0, stream>>>(kb, cosb, sinb, NKV);
    k_tv<<<dim3(64, 4, 16), tb, 0, stream>>>(vb, vtb);
    k_attn<<<dim3(16, 32, 2), 256, 0, stream>>>(qb, kb, vtb, hid);
    k_gemm_out<<<dim3(256), 512, 0, stream>>>(hid, wo_t, out);
}

// Round 5
// 672.313 us; speedup vs baseline: 1.4039x; 1.1933x over previous
//
#include <hip/hip_runtime.h>

// ============================================================================
// GLM4-MoE attention layer on MI355X (gfx950), fp16 MFMA pipeline.
// Round 5: attention latency surgery.
//   - exp2 via inline-asm v_exp_f32 (exp2f was likely an OCML libcall)
//   - Psm shrunk to per-wave [32][32] + 2-phase PV  -> LDS 72KB (2 blocks/CU)
//   - 1D grid with kvh = blockIdx%8: per-XCD KV working set = 4MB = its L2
//   - sched_barrier(0) dropped (lgkmcnt(0)+memory clobber orders LDS ops)
// GEMMs: round-4 256x256 8-wave phase-pipelined structure (proven).
// ============================================================================

typedef _Float16 f16;
typedef _Float16 f16x8 __attribute__((ext_vector_type(8)));
typedef float f32x4 __attribute__((ext_vector_type(4)));

static constexpr int Bn = 2, Sn = 2048, Hn = 4096, NH = 32, NKV = 8, HD = 128;
static constexpr float QSC = 0.08838834764831845f * 1.44269504088896340736f; // 1/sqrt(128)*log2e

#define AS1 __attribute__((address_space(1)))
#define AS3 __attribute__((address_space(3)))

__device__ __forceinline__ void async_ld16(const void* g, void* l) {
    __builtin_amdgcn_global_load_lds((const AS1 void*)g, (AS3 void*)l, 16, 0, 0);
}

__device__ __forceinline__ unsigned pk2(float a, float b) {
    unsigned r;
    asm("v_cvt_pkrtz_f16_f32 %0, %1, %2" : "=v"(r) : "v"(a), "v"(b));
    return r;
}

// native exp2: v_exp_f32 computes 2^x
__device__ __forceinline__ float fexp2(float x) {
    float r;
    asm("v_exp_f32 %0, %1" : "=v"(r) : "v"(x));
    return r;
}

// ---------------------------------------------------------------------------
__global__ void k_cvt(const float* __restrict__ src, f16* __restrict__ dst, long n) {
    long i = ((long)blockIdx.x * blockDim.x + threadIdx.x) * 8;
    if (i >= n) return;
    float4 a = *(const float4*)(src + i);
    float4 b = *(const float4*)(src + i + 4);
    f16x8 o = {(f16)a.x, (f16)a.y, (f16)a.z, (f16)a.w,
               (f16)b.x, (f16)b.y, (f16)b.z, (f16)b.w};
    *(f16x8*)(dst + i) = o;
}

// ---------------------------------------------------------------------------
__global__ void k_tcvt(const float* __restrict__ src, f16* __restrict__ dst,
                       int K, int N, long rs) {
    __shared__ float tile[32][33];
    int k0 = blockIdx.y * 32, n0 = blockIdx.x * 32;
    int tx = threadIdx.x, ty = threadIdx.y;
#pragma unroll
    for (int r = ty; r < 32; r += 8)
        tile[r][tx] = src[(long)(k0 + r) * N + (n0 + tx)];
    __syncthreads();
#pragma unroll
    for (int r = ty; r < 32; r += 8)
        dst[(long)(n0 + r) * rs + (k0 + tx)] = (f16)tile[tx][r];
}

// ---------------------------------------------------------------------------
__global__ void k_rope(f16* __restrict__ x, const float* __restrict__ cosb,
                       const float* __restrict__ sinb, int nheads) {
    long idx = (long)blockIdx.x * blockDim.x + threadIdx.x;
    int i = (int)(idx & 31);
    long t = idx >> 5;
    int s = (int)(t & (Sn - 1));
    int bh = (int)(t >> 11);
    int b = bh / nheads;
    long base = t * HD + 2 * i;
    float c = cosb[((long)b * Sn + s) * 64 + i];
    float sv = sinb[((long)b * Sn + s) * 64 + i];
    float x0 = (float)x[base], x1 = (float)x[base + 1];
    x[base]     = (f16)(x0 * c - x1 * sv);
    x[base + 1] = (f16)(x1 * c + x0 * sv);
}

// ---------------------------------------------------------------------------
__global__ void k_tv(const f16* __restrict__ v, f16* __restrict__ vt) {
    __shared__ f16 tile[32][33];
    int bk = blockIdx.z;
    int s0 = blockIdx.x * 32, d0 = blockIdx.y * 32;
    const f16* src = v + (long)bk * Sn * HD;
    f16* dst = vt + (long)bk * Sn * HD;
    int tx = threadIdx.x, ty = threadIdx.y;
#pragma unroll
    for (int r = ty; r < 32; r += 8)
        tile[r][tx] = src[(long)(s0 + r) * HD + (d0 + tx)];
    __syncthreads();
#pragma unroll
    for (int r = ty; r < 32; r += 8)
        dst[(long)(d0 + r) * Sn + (s0 + tx)] = tile[tx][r];
}

// ---------------------------------------------------------------------------
// 256x256 GEMM core, BK=64, 8 waves (2M x 4N), K=4096 fixed. (round-4 proven)
__device__ __forceinline__ void gemm256_core(
    const f16* __restrict__ A, const f16* __restrict__ Bt,
    char* L, int m0, int n0, f32x4 acc[8][4]) {
    const int t = threadIdx.x, lane = t & 63, wave = t >> 6;
    const int wm = wave >> 2, wn = wave & 3;
    const int fr = lane & 15, fg = lane >> 4;

    const int srow = wave * 8 + (lane >> 3);
    const int scol = 8 * ((lane & 7) ^ (lane >> 3));
    const f16* ga = A  + (long)(m0 + srow) * 4096 + scol;
    const f16* gb = Bt + (long)(n0 + srow) * 4096 + scol;
    const int dst0 = wave * 1024;

#pragma unroll
    for (int half = 0; half < 2; ++half)
#pragma unroll
        for (int inst = 0; inst < 2; ++inst) {
            async_ld16(ga + (long)(half * 128 + inst * 64) * 4096,
                       L + half * 16384 + inst * 8192 + dst0);
            async_ld16(gb + (long)(half * 128 + inst * 64) * 4096,
                       L + 32768 + half * 16384 + inst * 8192 + dst0);
        }
    asm volatile("s_waitcnt vmcnt(0)" ::: "memory");
    __builtin_amdgcn_s_barrier();

    const int aoff = wm * 16384;
    const int boff = 32768 + (wn >> 1) * 16384;
    const int brow = (wn & 1) * 64;
    const int swz = (fr & 7) << 4;

    for (int tt = 0; tt < 64; ++tt) {
        const int c = tt & 1;
        const char* bufA = L + c * 65536 + aoff;
        const char* bufB = L + c * 65536 + boff;
        char* outbuf = L + (c ^ 1) * 65536;
        const f16* gat = ga + (tt + 1) * 64;
        const f16* gbt = gb + (tt + 1) * 64;
        const bool more = (tt < 63);

#pragma unroll
        for (int ks = 0; ks < 2; ++ks) {
            const int cb = (ks * 64 + 16 * fg) ^ swz;
            f16x8 bf[4];
#pragma unroll
            for (int nf = 0; nf < 4; ++nf)
                bf[nf] = *(const f16x8*)(bufB + (brow + nf * 16 + fr) * 128 + cb);
#pragma unroll
            for (int mq = 0; mq < 2; ++mq) {
                f16x8 af[4];
#pragma unroll
                for (int i = 0; i < 4; ++i)
                    af[i] = *(const f16x8*)(bufA + (mq * 64 + i * 16 + fr) * 128 + cb);
                if (ks == 0 && more) {
                    if (mq == 0) {
#pragma unroll
                        for (int half = 0; half < 2; ++half)
#pragma unroll
                            for (int inst = 0; inst < 2; ++inst)
                                async_ld16(gat + (long)(half * 128 + inst * 64) * 4096,
                                           outbuf + half * 16384 + inst * 8192 + dst0);
                    } else {
#pragma unroll
                        for (int half = 0; half < 2; ++half)
#pragma unroll
                            for (int inst = 0; inst < 2; ++inst)
                                async_ld16(gbt + (long)(half * 128 + inst * 64) * 4096,
                                           outbuf + 32768 + half * 16384 + inst * 8192 + dst0);
                    }
                }
                __builtin_amdgcn_s_barrier();
                __builtin_amdgcn_s_setprio(1);
#pragma unroll
                for (int i = 0; i < 4; ++i)
#pragma unroll
                    for (int nf = 0; nf < 4; ++nf)
                        acc[mq * 4 + i][nf] = __builtin_amdgcn_mfma_f32_16x16x32_f16(
                            af[i], bf[nf], acc[mq * 4 + i][nf], 0, 0, 0);
                __builtin_amdgcn_s_setprio(0);
                if (ks == 1 && mq == 1)
                    asm volatile("s_waitcnt vmcnt(0)" ::: "memory");
                __builtin_amdgcn_s_barrier();
            }
        }
    }
}

// GEMM1: hidden[4096][4096] @ Wqkv^T[6144][4096] -> scatter q/k/v (Q pre-scaled)
__global__ __launch_bounds__(512) void k_gemm_qkv(
    const f16* __restrict__ A, const f16* __restrict__ Bt,
    f16* __restrict__ q, f16* __restrict__ kk_, f16* __restrict__ vv) {
    __shared__ __align__(16) char L[131072];
    const int bid = blockIdx.x;
    const int swzb = (bid & 7) * 48 + (bid >> 3);
    const int m0 = (swzb / 24) * 256, n0 = (swzb % 24) * 256;
    f32x4 acc[8][4] = {};
    gemm256_core(A, Bt, L, m0, n0, acc);

    const int lane = threadIdx.x & 63, wave = threadIdx.x >> 6;
    const int wm = wave >> 2, wn = wave & 3;
    const int fr = lane & 15, fg = lane >> 4;
#pragma unroll
    for (int mf = 0; mf < 8; ++mf) {
        int r0 = m0 + wm * 128 + mf * 16 + 4 * fg;
#pragma unroll
        for (int nf = 0; nf < 4; ++nf) {
            int cc = n0 + wn * 64 + nf * 16 + fr;
            int d = cc & 127;
#pragma unroll
            for (int e = 0; e < 4; ++e) {
                int r = r0 + e;
                int b = r >> 11, s = r & (Sn - 1);
                if (cc < 4096) {
                    int h = cc >> 7;
                    q[(((long)b * NH + h) * Sn + s) * HD + d] = (f16)(acc[mf][nf][e] * QSC);
                } else if (cc < 5120) {
                    int h = (cc - 4096) >> 7;
                    kk_[(((long)b * NKV + h) * Sn + s) * HD + d] = (f16)acc[mf][nf][e];
                } else {
                    int h = (cc - 5120) >> 7;
                    vv[(((long)b * NKV + h) * Sn + s) * HD + d] = (f16)acc[mf][nf][e];
                }
            }
        }
    }
}

// GEMM2: attn_out[4096][4096] @ wo^T[4096][4096] -> d_out f32
__global__ __launch_bounds__(512) void k_gemm_out(
    const f16* __restrict__ A, const f16* __restrict__ Bt,
    float* __restrict__ out) {
    __shared__ __align__(16) char L[131072];
    const int bid = blockIdx.x;
    const int swzb = (bid & 7) * 32 + (bid >> 3);
    const int m0 = (swzb >> 4) * 256, n0 = (swzb & 15) * 256;
    f32x4 acc[8][4] = {};
    gemm256_core(A, Bt, L, m0, n0, acc);

    const int lane = threadIdx.x & 63, wave = threadIdx.x >> 6;
    const int wm = wave >> 2, wn = wave & 3;
    const int fr = lane & 15, fg = lane >> 4;
#pragma unroll
    for (int mf = 0; mf < 8; ++mf) {
        int r0 = m0 + wm * 128 + mf * 16 + 4 * fg;
#pragma unroll
        for (int nf = 0; nf < 4; ++nf) {
            int cc = n0 + wn * 64 + nf * 16 + fr;
#pragma unroll
            for (int e = 0; e < 4; ++e)
                out[(long)(r0 + e) * 4096 + cc] = acc[mf][nf][e];
        }
    }
}

// ---------------------------------------------------------------------------
// Flash attention v4: swapped QK^T + in-lane softmax + defer-rescale (r3),
// native v_exp, Psm[32][32] 2-phase PV (LDS 72KB -> 2 blocks/CU),
// kvh-grouped 1D grid (per-XCD KV = 4MB = L2), K/V dbuf + vmcnt(8) + swizzle.

__device__ __forceinline__ f16x8 ld_sw256(const f16* base, int r, int c) {
    int byte = r * 256 + ((c * 2) ^ ((r & 7) << 4));
    return *(const f16x8*)((const char*)base + byte);
}
__device__ __forceinline__ f16x8 ld_sw128(const f16* base, int r, int c) {
    int byte = r * 128 + ((c * 2) ^ ((r & 7) << 4));
    return *(const f16x8*)((const char*)base + byte);
}

__device__ __forceinline__ void stage_k(const f16* __restrict__ Kb, f16* ksm,
                                        int k0, int wave, int lane) {
#pragma unroll
    for (int i = 0; i < 4; ++i) {
        int dbase = (i * 4 + wave) * 1024;
        int d = dbase + lane * 16;
        int row = d >> 8;
        int cb = (d & 255) ^ ((row & 7) << 4);
        async_ld16(Kb + (long)(k0 + row) * HD + (cb >> 1), (char*)ksm + dbase);
    }
}
__device__ __forceinline__ void stage_v(const f16* __restrict__ Vb, f16* vsm,
                                        int k0, int wave, int lane) {
#pragma unroll
    for (int i = 0; i < 4; ++i) {
        int dbase = (i * 4 + wave) * 1024;
        int d = dbase + lane * 16;
        int row = d >> 7;
        int cb = (d & 127) ^ ((row & 7) << 4);
        async_ld16(Vb + (long)row * Sn + k0 + (cb >> 1), (char*)vsm + dbase);
    }
}

__global__ __launch_bounds__(256) void k_attn(
    const f16* __restrict__ Q, const f16* __restrict__ K,
    const f16* __restrict__ Vt, f16* __restrict__ O) {
    __shared__ __align__(16) f16 Ksm[2][64 * 128];   // 32KB
    __shared__ __align__(16) f16 Vsm[2][128 * 64];   // 32KB
    __shared__ __align__(16) f16 Psm[4][32 * 32];    // 8KB, per-wave [32 q][32 kv]

    // 1D grid 1024: id = ((b*4 + hg)*16 + (15-qt))*8 + kvh
    const int id = blockIdx.x;
    const int kvh = id & 7;                 // -> XCD via %8 round-robin
    const int r_ = id >> 3;
    const int qt = 15 - (r_ & 15);          // heavy-first within group
    const int hg = (r_ >> 4) & 3;
    const int b  = r_ >> 6;
    const int h  = kvh * 4 + hg;
    const int q0 = qt * 128;
    const int t = threadIdx.x, lane = t & 63, wave = t >> 6;
    const int q0w = q0 + wave * 32;
    const int fr = lane & 15, fg = lane >> 4;

    const f16* Qb = Q + ((long)(b * NH + h) * Sn) * HD;
    const f16* Kb = K + ((long)(b * NKV + kvh) * Sn) * HD;
    const f16* Vb = Vt + ((long)(b * NKV + kvh) * HD) * Sn;

    f16x8 qf[2][4];
#pragma unroll
    for (int mq = 0; mq < 2; ++mq)
#pragma unroll
        for (int kk = 0; kk < 4; ++kk)
            qf[mq][kk] = *(const f16x8*)&Qb[(long)(q0w + mq * 16 + fr) * HD + kk * 32 + 8 * fg];

    f32x4 oacc[2][8] = {};
    float mrun[2] = {-1e30f, -1e30f};
    float lrun[2] = {0.f, 0.f};

    const int nt = q0 / 64 + 2;
    stage_k(Kb, Ksm[0], 0, wave, lane);
    stage_v(Vb, Vsm[0], 0, wave, lane);

    for (int kt = 0; kt < nt; ++kt) {
        const int k0 = kt * 64;
        const int cur = kt & 1;
        if (kt + 1 < nt) {
            stage_k(Kb, Ksm[cur ^ 1], (kt + 1) * 64, wave, lane);
            stage_v(Vb, Vsm[cur ^ 1], (kt + 1) * 64, wave, lane);
            asm volatile("s_waitcnt vmcnt(8)" ::: "memory");
        } else {
            asm volatile("s_waitcnt vmcnt(0)" ::: "memory");
        }
        __builtin_amdgcn_s_barrier();

        if (k0 <= q0w + 31) {
            // ---- S^T = K . Q^T : kv = 16nn+4fg+e (rows), q = 16mq+fr (cols)
            f32x4 st[4][2] = {};
#pragma unroll
            for (int kk = 0; kk < 4; ++kk)
#pragma unroll
                for (int nn = 0; nn < 4; ++nn) {
                    f16x8 kf = ld_sw256(Ksm[cur], nn * 16 + fr, kk * 32 + 8 * fg);
#pragma unroll
                    for (int mq = 0; mq < 2; ++mq)
                        st[nn][mq] = __builtin_amdgcn_mfma_f32_16x16x32_f16(
                            kf, qf[mq][kk], st[nn][mq], 0, 0, 0);
                }
            // ---- mask only on diagonal tile
            const bool full = (k0 + 63 <= q0w);
            if (!full) {
#pragma unroll
                for (int nn = 0; nn < 4; ++nn)
#pragma unroll
                    for (int mq = 0; mq < 2; ++mq)
#pragma unroll
                        for (int e = 0; e < 4; ++e) {
                            int kv = k0 + 16 * nn + 4 * fg + e;
                            int qq = q0w + 16 * mq + fr;
                            if (kv > qq) st[nn][mq][e] = -1e30f;
                        }
            }
            // ---- row max: in-lane + cross-fg
            float pmax[2];
#pragma unroll
            for (int mq = 0; mq < 2; ++mq) {
                float m0v = fmaxf(fmaxf(st[0][mq][0], st[0][mq][1]),
                                  fmaxf(st[0][mq][2], st[0][mq][3]));
#pragma unroll
                for (int nn = 1; nn < 4; ++nn) {
                    float mv = fmaxf(fmaxf(st[nn][mq][0], st[nn][mq][1]),
                                     fmaxf(st[nn][mq][2], st[nn][mq][3]));
                    m0v = fmaxf(m0v, mv);
                }
                m0v = fmaxf(m0v, __shfl_xor(m0v, 16, 64));
                m0v = fmaxf(m0v, __shfl_xor(m0v, 32, 64));
                pmax[mq] = m0v;
            }
            // ---- defer-rescale (T13)
            bool need = (pmax[0] > mrun[0] + 8.f) || (pmax[1] > mrun[1] + 8.f);
            if (__any(need)) {
#pragma unroll
                for (int mq = 0; mq < 2; ++mq) {
                    float mn = fmaxf(mrun[mq], pmax[mq]);
                    float sc = fexp2(mrun[mq] - mn);
                    mrun[mq] = mn;
                    lrun[mq] *= sc;
                    float scr[4];
#pragma unroll
                    for (int e = 0; e < 4; ++e)
                        scr[e] = __shfl(sc, (lane & 48) | (4 * fg + e), 64);
#pragma unroll
                    for (int nd = 0; nd < 8; ++nd)
#pragma unroll
                        for (int e = 0; e < 4; ++e)
                            oacc[mq][nd][e] *= scr[e];
                }
            }
            // ---- 2-phase: P-store [32 q][32 kv] + PV for that kv half.
            // Psm row = 64B; granule rotation: byte = r*64 + ((cb + 16*((r>>1)&3)) & 63)
#pragma unroll
            for (int ph = 0; ph < 2; ++ph) {
#pragma unroll
                for (int mq = 0; mq < 2; ++mq) {
                    int row = 16 * mq + fr;
                    int rot = ((row >> 1) & 3) << 4;
                    char* pbase = (char*)&Psm[wave][0] + row * 64;
#pragma unroll
                    for (int nh = 0; nh < 2; ++nh) {
                        int nn = 2 * ph + nh;
                        float p0 = fexp2(st[nn][mq][0] - mrun[mq]);
                        float p1 = fexp2(st[nn][mq][1] - mrun[mq]);
                        float p2 = fexp2(st[nn][mq][2] - mrun[mq]);
                        float p3 = fexp2(st[nn][mq][3] - mrun[mq]);
                        lrun[mq] += (p0 + p1) + (p2 + p3);
                        uint2 w = {pk2(p0, p1), pk2(p2, p3)};
                        *(uint2*)(pbase + ((32 * nh + 8 * fg + rot) & 63)) = w;
                    }
                }
                asm volatile("s_waitcnt lgkmcnt(0)" ::: "memory");
                f16x8 pf[2];
#pragma unroll
                for (int mq = 0; mq < 2; ++mq) {
                    int row = 16 * mq + fr;
                    int rot = ((row >> 1) & 3) << 4;
                    pf[mq] = *(const f16x8*)((char*)&Psm[wave][0] + row * 64 +
                                             ((16 * fg + rot) & 63));
                }
#pragma unroll
                for (int nd = 0; nd < 8; ++nd) {
                    f16x8 vf = ld_sw128(Vsm[cur], nd * 16 + fr, ph * 32 + 8 * fg);
#pragma unroll
                    for (int mq = 0; mq < 2; ++mq)
                        oacc[mq][nd] = __builtin_amdgcn_mfma_f32_16x16x32_f16(
                            pf[mq], vf, oacc[mq][nd], 0, 0, 0);
                }
            }
        }
        __builtin_amdgcn_s_barrier();
    }

    // ---- epilogue
#pragma unroll
    for (int mq = 0; mq < 2; ++mq) {
        lrun[mq] += __shfl_xor(lrun[mq], 16, 64);
        lrun[mq] += __shfl_xor(lrun[mq], 32, 64);
    }
#pragma unroll
    for (int mq = 0; mq < 2; ++mq) {
        float li = 1.f / lrun[mq];
        float ir[4];
#pragma unroll
        for (int e = 0; e < 4; ++e)
            ir[e] = __shfl(li, (lane & 48) | (4 * fg + e), 64);
#pragma unroll
        for (int nd = 0; nd < 8; ++nd)
#pragma unroll
            for (int e = 0; e < 4; ++e) {
                int srow = q0w + mq * 16 + 4 * fg + e;
                long tok = (long)b * Sn + srow;
                O[tok * (NH * HD) + h * HD + nd * 16 + fr] = (f16)(oacc[mq][nd][e] * ir[e]);
            }
    }
}

// sentinel if workspace too small
__global__ void k_ws_fail(float* out) { out[0] = 1.0e9f; }

// ---------------------------------------------------------------------------
extern "C" void kernel_launch(void* const* d_in, const int* in_sizes, int n_in,
                              void* d_out, int out_size, void* d_ws, size_t ws_size,
                              hipStream_t stream) {
    const float* hs   = (const float*)d_in[0];
    const float* wq   = (const float*)d_in[1];
    const float* wk   = (const float*)d_in[2];
    const float* wv   = (const float*)d_in[3];
    const float* wo   = (const float*)d_in[4];
    const float* cosb = (const float*)d_in[5];
    const float* sinb = (const float*)d_in[6];
    float* out = (float*)d_out;

    const size_t OFF_WQKV = 0;
    const size_t OFF_WO   = 50331648;
    const size_t OFF_HID  = 83886080;
    const size_t OFF_Q    = 117440512;
    const size_t OFF_K    = 150994944;
    const size_t OFF_V    = 159383552;
    const size_t OFF_VT   = 167772160;
    const size_t WS_NEED  = 176160768;
    if (ws_size < WS_NEED) { k_ws_fail<<<1, 1, 0, stream>>>(out); return; }

    char* ws = (char*)d_ws;
    f16* wqkv_t = (f16*)(ws + OFF_WQKV);
    f16* wo_t   = (f16*)(ws + OFF_WO);
    f16* hid    = (f16*)(ws + OFF_HID);
    f16* qb     = (f16*)(ws + OFF_Q);
    f16* kb     = (f16*)(ws + OFF_K);
    f16* vb     = (f16*)(ws + OFF_V);
    f16* vtb    = (f16*)(ws + OFF_VT);

    dim3 tb(32, 8);
    k_cvt<<<dim3(16777216 / (256 * 8)), 256, 0, stream>>>(hs, hid, 16777216L);
    k_tcvt<<<dim3(128, 128), tb, 0, stream>>>(wq, wqkv_t, 4096, 4096, 4096);
    k_tcvt<<<dim3(32, 128),  tb, 0, stream>>>(wk, wqkv_t + (long)4096 * 4096, 4096, 1024, 4096);
    k_tcvt<<<dim3(32, 128),  tb, 0, stream>>>(wv, wqkv_t + (long)5120 * 4096, 4096, 1024, 4096);
    k_tcvt<<<dim3(128, 128), tb, 0, stream>>>(wo, wo_t, 4096, 4096, 4096);
    k_gemm_qkv<<<dim3(384), 512, 0, stream>>>(hid, wqkv_t, qb, kb, vb);
    k_rope<<<dim3(2 * 32 * 2048 * 32 / 256), 256, 0, stream>>>(qb, cosb, sinb, NH);
    k_rope<<<dim3(2 * 8 * 2048 * 32 / 256), 256, 0, stream>>>(kb, cosb, sinb, NKV);
    k_tv<<<dim3(64, 4, 16), tb, 0, stream>>>(vb, vtb);
    k_attn<<<dim3(1024), 256, 0, stream>>>(qb, kb, vtb, hid);
    k_gemm_out<<<dim3(256), 512, 0, stream>>>(hid, wo_t, out);
}